// Round 3
// baseline (114.786 us; speedup 1.0000x reference)
//
#include <hip/hip_runtime.h>
#include <stdint.h>

// ---------------------------------------------------------------------------
// SlidingAttentionModule: B=2, S=2048, D=1024, H=16, hd=64, window +-8
//   qkv = x @ w_qkv^T + b_qkv     (bf16 MFMA GEMM -> Q,K [bh,s,d], V^T [bh,d,s])
//   attn: MFMA-tiled 16-query x 32-key sliding window, no max-subtraction
//   out = ctx @ w_out^T + b_out   (bf16 MFMA GEMM, fp32 out)
// GEMM: 128x128 tile, BK=32, 2-phase double-buffered global_load_lds prefetch,
//       conflict-free 16B-granule LDS layout [rowhi][kchunk][rowlo].
// ---------------------------------------------------------------------------

typedef __bf16 bf16_t;
typedef bf16_t bf16x8 __attribute__((ext_vector_type(8)));
typedef unsigned short u16x8 __attribute__((ext_vector_type(8)));
typedef float f32x4 __attribute__((ext_vector_type(4)));

#define GLD16(g, l)                                                        \
  __builtin_amdgcn_global_load_lds(                                        \
      (const __attribute__((address_space(1))) void*)(g),                  \
      (__attribute__((address_space(3))) void*)(l), 16, 0, 0)

__device__ __forceinline__ unsigned short f2bf(float f) {
  unsigned int u = __float_as_uint(f);
  u += 0x7FFFu + ((u >> 16) & 1u);  // round-to-nearest-even
  return (unsigned short)(u >> 16);
}

__device__ __forceinline__ bf16x8 ld16(const unsigned short* p) {
  return __builtin_bit_cast(bf16x8, *reinterpret_cast<const u16x8*>(p));
}

// --- fp32 -> bf16 conversion, 4 elems/thread --------------------------------
__global__ void cvt_f32_bf16(const float* __restrict__ in,
                             unsigned short* __restrict__ out, int n4) {
  int i = blockIdx.x * blockDim.x + threadIdx.x;
  if (i >= n4) return;
  const float4 f = reinterpret_cast<const float4*>(in)[i];
  ushort4 o;
  o.x = f2bf(f.x); o.y = f2bf(f.y); o.z = f2bf(f.z); o.w = f2bf(f.w);
  reinterpret_cast<ushort4*>(out)[i] = o;
}

// --- bf16 GEMM: C[m,n] = sum_k A[m,k]*Bt[n,k] + bias[n] ---------------------
// LDS layout (per 128x32 tile): 16B granule g = rowhi*64 + kchunk*16 + rowlo
//   (row = rowhi*16+rowlo, k = kchunk*8 + 0..7). Stage: lane u of wave w loads
//   global row w*16+(u&15), kchunk u>>4 -> LDS dest = wavebase + u*16B
//   (linear, as global_load_lds requires). Fragment read at (row, kg*8) is
//   granule wr*256+f*64+lane -> 64 lanes read 1KB contiguous: conflict-free.
// EPI=0: plain fp32 write to Cp[m*N+n].
// EPI=1: scatter bf16 q/k into [bh,s,64], v into [bh,d,2048] (transposed).
template <int EPI>
__global__ __launch_bounds__(256, 2) void gemm_bt(
    const unsigned short* __restrict__ A,   // [M,K] bf16 bits
    const unsigned short* __restrict__ Bt,  // [N,K] bf16 bits
    const float* __restrict__ bias,         // [N]
    unsigned short* __restrict__ Cq, unsigned short* __restrict__ Ck,
    unsigned short* __restrict__ Cv, float* __restrict__ Cp, int M, int N,
    int K) {
  __shared__ unsigned short sA[2][4096];
  __shared__ unsigned short sB[2][4096];

  const int tid = threadIdx.x;
  const int wave = tid >> 6;
  const int lane = tid & 63;
  const int m0 = blockIdx.x * 128;
  const int n0 = blockIdx.y * 128;
  const int wr = wave >> 1;
  const int wc = wave & 1;

  f32x4 acc[4][4] = {};

  // staging source: lane u -> row w*16+(u&15), k-offset (u>>4)*8
  const int srow = (wave << 4) + (lane & 15);
  const int skc = (lane >> 4) << 3;
  const unsigned short* Ag0 = A + (size_t)(m0 + srow) * K + skc;
  const unsigned short* Ag1 = Ag0 + (size_t)64 * K;
  const unsigned short* Bg0 = Bt + (size_t)(n0 + srow) * K + skc;
  const unsigned short* Bg1 = Bg0 + (size_t)64 * K;
  const int wb0 = wave * 512;         // ushort offset of wave's granule block
  const int wb1 = 2048 + wave * 512;  // second 64-row half

  // prologue: stage tile 0 into buffer 0
  GLD16(Ag0, &sA[0][wb0]);
  GLD16(Ag1, &sA[0][wb1]);
  GLD16(Bg0, &sB[0][wb0]);
  GLD16(Bg1, &sB[0][wb1]);
  __syncthreads();

  int cur = 0;
  for (int k0 = 0; k0 < K; k0 += 32) {
    const int nxt = cur ^ 1;
    if (k0 + 32 < K) {  // prefetch next tile; drains at end-of-iter barrier
      GLD16(Ag0 + k0 + 32, &sA[nxt][wb0]);
      GLD16(Ag1 + k0 + 32, &sA[nxt][wb1]);
      GLD16(Bg0 + k0 + 32, &sB[nxt][wb0]);
      GLD16(Bg1 + k0 + 32, &sB[nxt][wb1]);
    }
    bf16x8 af[4], bfr[4];
#pragma unroll
    for (int f = 0; f < 4; ++f) {
      af[f] = ld16(&sA[cur][(wr * 256 + f * 64 + lane) * 8]);
      bfr[f] = ld16(&sB[cur][(wc * 256 + f * 64 + lane) * 8]);
    }
#pragma unroll
    for (int i = 0; i < 4; ++i)
#pragma unroll
      for (int j = 0; j < 4; ++j)
        acc[i][j] =
            __builtin_amdgcn_mfma_f32_16x16x32_bf16(af[i], bfr[j], acc[i][j], 0, 0, 0);
    __syncthreads();  // lgkm: reads done; vmcnt(0): prefetch landed
    cur = nxt;
  }

  // epilogue: C/D layout col = lane&15, row = (lane>>4)*4 + reg  [m89]
#pragma unroll
  for (int i = 0; i < 4; ++i) {
    const int row0 = m0 + wr * 64 + i * 16 + ((lane >> 4) << 2);
#pragma unroll
    for (int j = 0; j < 4; ++j) {
      const int col = n0 + wc * 64 + j * 16 + (lane & 15);
      const float bb = bias[col];
#pragma unroll
      for (int r = 0; r < 4; ++r) {
        const int m = row0 + r;
        const float val = acc[i][j][r] + bb;
        if (EPI == 0) {
          Cp[(size_t)m * N + col] = val;
        } else {
          const int b = m >> 11, s = m & 2047;
          const int which = col >> 10, nn = col & 1023;
          const int h = nn >> 6, d = nn & 63;
          const int bh = (b << 4) + h;
          const unsigned short vb = f2bf(val);
          if (which == 0)
            Cq[((size_t)(bh * 2048 + s)) * 64 + d] = vb;
          else if (which == 1)
            Ck[((size_t)(bh * 2048 + s)) * 64 + d] = vb;
          else
            Cv[((size_t)(bh * 64 + d)) * 2048 + s] = vb;
        }
      }
    }
  }
}

// --- MFMA sliding attention: 1 wave = 16 queries x 32-key window ------------
// Q,K: [bh, s, 64] bf16.  Vt: [bh, d, 2048] bf16.  ctx out: [b, s, 1024] bf16.
__global__ __launch_bounds__(256) void attn_mfma(
    const unsigned short* __restrict__ Qb, const unsigned short* __restrict__ Kb,
    const unsigned short* __restrict__ Vt, unsigned short* __restrict__ ctx) {
  __shared__ unsigned short P[4][16][40];  // per-wave P tile, padded stride 40
  const int wave = threadIdx.x >> 6;
  const int lane = threadIdx.x & 63;
  const int gw = (blockIdx.x << 2) + wave;
  const int bh = gw >> 7;           // 0..31
  const int i0 = (gw & 127) << 4;   // query tile start
  const int qr = lane & 15;
  const int kg = lane >> 4;         // 0..3
  const int kc = kg << 3;           // k-offset

  // Q A-fragments (row = query qr, k = dim)
  const size_t qbase = ((size_t)(bh * 2048 + i0 + qr)) * 64;
  const bf16x8 aq0 = ld16(Qb + qbase + kc);
  const bf16x8 aq1 = ld16(Qb + qbase + 32 + kc);

  // QK^T: 2 key-tiles x 2 k-steps. B-frag: row = key (lane&15), k = dim.
  f32x4 sc0 = {0.f, 0.f, 0.f, 0.f}, sc1 = {0.f, 0.f, 0.f, 0.f};
  {
    const int ka0 = i0 - 8 + qr;
    const int ka1 = ka0 + 16;
    const int kcl0 = min(max(ka0, 0), 2047);
    const int kcl1 = min(max(ka1, 0), 2047);
    const unsigned short* K0 = Kb + ((size_t)(bh * 2048 + kcl0)) * 64;
    const unsigned short* K1 = Kb + ((size_t)(bh * 2048 + kcl1)) * 64;
    sc0 = __builtin_amdgcn_mfma_f32_16x16x32_bf16(aq0, ld16(K0 + kc), sc0, 0, 0, 0);
    sc0 = __builtin_amdgcn_mfma_f32_16x16x32_bf16(aq1, ld16(K0 + 32 + kc), sc0, 0, 0, 0);
    sc1 = __builtin_amdgcn_mfma_f32_16x16x32_bf16(aq0, ld16(K1 + kc), sc1, 0, 0, 0);
    sc1 = __builtin_amdgcn_mfma_f32_16x16x32_bf16(aq1, ld16(K1 + 32 + kc), sc1, 0, 0, 0);
  }

  // mask + exp (no max-subtraction: |score| <= |q||k|/8, exp finite in fp32),
  // row-sum over 32 keys, stash P (bf16) in wave-private LDS.
  unsigned short* Pw = &P[wave][0][0];
  float lsum[4];
#pragma unroll
  for (int r = 0; r < 4; ++r) {
    const int q = (kg << 2) + r;   // score row = query
    const int key0 = qr, key1 = 16 + qr;
    const int ka0 = i0 - 8 + key0, ka1 = i0 - 8 + key1;
    const bool v0 = (q <= key0) && (key0 <= q + 16) && (ka0 >= 0) && (ka0 < 2048);
    const bool v1 = (q <= key1) && (key1 <= q + 16) && (ka1 >= 0) && (ka1 < 2048);
    const float e0 = v0 ? __expf(sc0[r] * 0.125f) : 0.f;
    const float e1 = v1 ? __expf(sc1[r] * 0.125f) : 0.f;
    Pw[q * 40 + key0] = f2bf(e0);
    Pw[q * 40 + key1] = f2bf(e1);
    float s = e0 + e1;
#pragma unroll
    for (int off = 1; off < 16; off <<= 1) s += __shfl_xor(s, off);
    lsum[r] = s;  // sum for query q, matches C-layout rows below
  }

  // P A-fragment: row = query qr, k = key
  const bf16x8 pa = ld16(&Pw[qr * 40 + kc]);

  // PV: 4 d-tiles, K=32 keys in one MFMA. B-frag from Vt: row = d, k = key.
  const int base_s = min(max(i0 - 8 + kc, 0), 2040);  // clamped chunks are fully masked
  f32x4 o[4];
  const f32x4 zero = {0.f, 0.f, 0.f, 0.f};
#pragma unroll
  for (int t2 = 0; t2 < 4; ++t2) {
    const unsigned short* Vr =
        Vt + ((size_t)(bh * 64 + t2 * 16 + qr)) * 2048 + base_s;
    o[t2] = __builtin_amdgcn_mfma_f32_16x16x32_bf16(pa, ld16(Vr), zero, 0, 0, 0);
  }

  // normalize + write ctx [b, s, 1024]
  const int b = bh >> 4, h = bh & 15;
  float rinv[4];
#pragma unroll
  for (int r = 0; r < 4; ++r) rinv[r] = 1.0f / lsum[r];
#pragma unroll
  for (int t2 = 0; t2 < 4; ++t2) {
#pragma unroll
    for (int r = 0; r < 4; ++r) {
      const int q = (kg << 2) + r;
      const int d = t2 * 16 + qr;
      ctx[((size_t)(b * 2048 + i0 + q)) * 1024 + (h << 6) + d] =
          f2bf(o[t2][r] * rinv[r]);
    }
  }
}

// ---------------------------------------------------------------------------
extern "C" void kernel_launch(void* const* d_in, const int* in_sizes, int n_in,
                              void* d_out, int out_size, void* d_ws,
                              size_t ws_size, hipStream_t stream) {
  const float* x = (const float*)d_in[0];      // [2,2048,1024]
  // d_in[1] token_ids: unused by reference
  const float* w_qkv = (const float*)d_in[2];  // [3072,1024]
  const float* b_qkv = (const float*)d_in[3];  // [3072]
  const float* w_out = (const float*)d_in[4];  // [1024,1024]
  const float* b_out = (const float*)d_in[5];  // [1024]
  float* out = (float*)d_out;                  // [2,2048,1024] fp32

  char* ws = (char*)d_ws;
  unsigned short* xb    = (unsigned short*)(ws + 0);         // 8 MB
  unsigned short* wqkvb = (unsigned short*)(ws + 8388608);   // 6 MB
  unsigned short* woutb = (unsigned short*)(ws + 14680064);  // 2 MB
  unsigned short* Qb    = (unsigned short*)(ws + 16777216);  // 8 MB [bh,s,64]
  unsigned short* Kb    = (unsigned short*)(ws + 25165824);  // 8 MB [bh,s,64]
  unsigned short* Vt    = (unsigned short*)(ws + 33554432);  // 8 MB [bh,d,2048]
  unsigned short* ctxb  = (unsigned short*)(ws + 41943040);  // 8 MB [b,s,1024]

  // fp32 -> bf16 conversions
  cvt_f32_bf16<<<(1048576 + 255) / 256, 256, 0, stream>>>(x, xb, 1048576);
  cvt_f32_bf16<<<(786432 + 255) / 256, 256, 0, stream>>>(w_qkv, wqkvb, 786432);
  cvt_f32_bf16<<<(262144 + 255) / 256, 256, 0, stream>>>(w_out, woutb, 262144);

  // QKV projection: M=4096, N=3072, K=1024 -> bf16 Q/K/Vt scatter
  gemm_bt<1><<<dim3(32, 24), 256, 0, stream>>>(xb, wqkvb, b_qkv, Qb, Kb, Vt,
                                               nullptr, 4096, 3072, 1024);

  // sliding attention: 4096 waves (16 queries each), 4 waves/block
  attn_mfma<<<1024, 256, 0, stream>>>(Qb, Kb, Vt, ctxb);

  // out projection: M=4096, N=1024, K=1024 -> fp32 d_out
  gemm_bt<0><<<dim3(32, 8), 256, 0, stream>>>(ctxb, woutb, b_out, nullptr,
                                              nullptr, nullptr, out, 4096,
                                              1024, 1024);
}

// Round 4
// 80.398 us; speedup vs baseline: 1.4277x; 1.4277x over previous
//
#include <hip/hip_runtime.h>
#include <stdint.h>

// ---------------------------------------------------------------------------
// SlidingAttentionModule: B=2, S=2048, D=1024, H=16, hd=64, window +-8
//   qkv = x @ w_qkv^T + b_qkv     (bf16 MFMA GEMM -> Q,K [bh,s,d], V^T [bh,d,s])
//   attn: MFMA-tiled 16-query x 32-key sliding window, no max-subtraction
//   out = ctx @ w_out^T + b_out   (bf16 MFMA GEMM, fp32 out)
// GEMM: 128x128 tile, BK=64, single-buffer 2-barrier (round-2 proven sync),
//       row-major [128][64] LDS with slot^=(row&7) read-swizzle; the global
//       source is pre-permuted within each 128B row segment so coalescing is
//       preserved and the global_load_lds dest stays linear (rule #21).
// ---------------------------------------------------------------------------

typedef __bf16 bf16_t;
typedef bf16_t bf16x8 __attribute__((ext_vector_type(8)));
typedef unsigned short u16x8 __attribute__((ext_vector_type(8)));
typedef float f32x4 __attribute__((ext_vector_type(4)));

#define GLD16(g, l)                                                        \
  __builtin_amdgcn_global_load_lds(                                        \
      (const __attribute__((address_space(1))) void*)(g),                  \
      (__attribute__((address_space(3))) void*)(l), 16, 0, 0)

__device__ __forceinline__ unsigned short f2bf(float f) {
  unsigned int u = __float_as_uint(f);
  u += 0x7FFFu + ((u >> 16) & 1u);  // round-to-nearest-even
  return (unsigned short)(u >> 16);
}

__device__ __forceinline__ bf16x8 ld16(const unsigned short* p) {
  return __builtin_bit_cast(bf16x8, *reinterpret_cast<const u16x8*>(p));
}

// --- fp32 -> bf16 conversion of all three tensors, one launch ---------------
__global__ void cvt_all(const float* __restrict__ x, const float* __restrict__ wq,
                        const float* __restrict__ wo, unsigned short* __restrict__ xb,
                        unsigned short* __restrict__ wqb,
                        unsigned short* __restrict__ wob) {
  const int N0 = 1048576, N1 = 786432, N2 = 262144;  // float4 counts
  for (int i = blockIdx.x * blockDim.x + threadIdx.x; i < N0 + N1 + N2;
       i += gridDim.x * blockDim.x) {
    const float4* src;
    unsigned short* dst;
    int j;
    if (i < N0) { src = (const float4*)x; dst = xb; j = i; }
    else if (i < N0 + N1) { src = (const float4*)wq; dst = wqb; j = i - N0; }
    else { src = (const float4*)wo; dst = wob; j = i - N0 - N1; }
    const float4 f = src[j];
    ushort4 o;
    o.x = f2bf(f.x); o.y = f2bf(f.y); o.z = f2bf(f.z); o.w = f2bf(f.w);
    reinterpret_cast<ushort4*>(dst)[j] = o;
  }
}

// --- bf16 GEMM: C[m,n] = sum_k A[m,k]*Bt[n,k] + bias[n] ---------------------
// LDS: row-major [128][64] ushort; 16B slot s at (row) holds global k-slot
//   s ^ (row&7). Staging: instr i (=wave*4+r... see below) covers rows
//   [i*8, i*8+8); lane u -> row i*8+(u>>3), global slot (u&7)^(u>>3);
//   dest = linear wave-uniform base + lane*16B. 8 lanes span one 128B row
//   segment (permuted within) -> full coalescing.
// Fragment read: row r, k-step st, kgroup kg: slot_eff = (st*4+kg)^(r&7);
//   64 lanes spread over all 32 banks at the 128B/cy LDS floor.
// EPI=0: plain fp32 write to Cp[m*N+n].
// EPI=1: scatter bf16 q/k into [bh,s,64], v into [bh,d,2048] (transposed).
template <int EPI>
__global__ __launch_bounds__(256, 2) void gemm_bt(
    const unsigned short* __restrict__ A,   // [M,K] bf16 bits
    const unsigned short* __restrict__ Bt,  // [N,K] bf16 bits
    const float* __restrict__ bias,         // [N]
    unsigned short* __restrict__ Cq, unsigned short* __restrict__ Ck,
    unsigned short* __restrict__ Cv, float* __restrict__ Cp, int M, int N,
    int K) {
  __shared__ unsigned short sA[128 * 64];
  __shared__ unsigned short sB[128 * 64];

  const int tid = threadIdx.x;
  const int wave = tid >> 6;
  const int lane = tid & 63;
  const int m0 = blockIdx.x * 128;
  const int n0 = blockIdx.y * 128;
  const int wr = wave >> 1;
  const int wc = wave & 1;

  f32x4 acc[4][4] = {};

  // staging: lane u -> row wave*8 + (u>>3) (+r*32), global slot (u&7)^(u>>3)
  const int srow = (wave << 3) + (lane >> 3);
  const int sslot = ((lane & 7) ^ (lane >> 3)) << 3;  // elem offset in row
  const unsigned short* Ag = A + (size_t)(m0 + srow) * K + sslot;
  const unsigned short* Bg = Bt + (size_t)(n0 + srow) * K + sslot;
  const int wdst = wave * 512;  // ushort; + r*2048 per round; +lane*8 implicit

  const int kg = lane >> 4;
  const int l7 = lane & 7;

  for (int k0 = 0; k0 < K; k0 += 64) {
    __syncthreads();  // previous compute done before overwrite
#pragma unroll
    for (int r = 0; r < 4; ++r) {
      GLD16(Ag + (size_t)(r * 32) * K + k0, &sA[r * 2048 + wdst]);
      GLD16(Bg + (size_t)(r * 32) * K + k0, &sB[r * 2048 + wdst]);
    }
    __syncthreads();  // implicit vmcnt(0) drain -> staging complete

    bf16x8 af[2][4], bfr[2][4];
#pragma unroll
    for (int st = 0; st < 2; ++st) {
#pragma unroll
      for (int f = 0; f < 4; ++f) {
        const int ar = wr * 64 + f * 16 + (lane & 15);
        const int br = wc * 64 + f * 16 + (lane & 15);
        const int se = ((st << 2) | kg) ^ l7;
        af[st][f] = ld16(&sA[ar * 64 + (se << 3)]);
        bfr[st][f] = ld16(&sB[br * 64 + (se << 3)]);
      }
    }
#pragma unroll
    for (int st = 0; st < 2; ++st)
#pragma unroll
      for (int i = 0; i < 4; ++i)
#pragma unroll
        for (int j = 0; j < 4; ++j)
          acc[i][j] = __builtin_amdgcn_mfma_f32_16x16x32_bf16(
              af[st][i], bfr[st][j], acc[i][j], 0, 0, 0);
  }

  // epilogue: C/D layout col = lane&15, row = (lane>>4)*4 + reg  [m89]
#pragma unroll
  for (int i = 0; i < 4; ++i) {
    const int row0 = m0 + wr * 64 + i * 16 + ((lane >> 4) << 2);
#pragma unroll
    for (int j = 0; j < 4; ++j) {
      const int col = n0 + wc * 64 + j * 16 + (lane & 15);
      const float bb = bias[col];
#pragma unroll
      for (int r = 0; r < 4; ++r) {
        const int m = row0 + r;
        const float val = acc[i][j][r] + bb;
        if (EPI == 0) {
          Cp[(size_t)m * N + col] = val;
        } else {
          const int b = m >> 11, s = m & 2047;
          const int which = col >> 10, nn = col & 1023;
          const int h = nn >> 6, d = nn & 63;
          const int bh = (b << 4) + h;
          const unsigned short vb = f2bf(val);
          if (which == 0)
            Cq[((size_t)(bh * 2048 + s)) * 64 + d] = vb;
          else if (which == 1)
            Ck[((size_t)(bh * 2048 + s)) * 64 + d] = vb;
          else
            Cv[((size_t)(bh * 64 + d)) * 2048 + s] = vb;
        }
      }
    }
  }
}

// --- MFMA sliding attention: 1 wave = 16 queries x 32-key window ------------
// Q,K: [bh, s, 64] bf16.  Vt: [bh, d, 2048] bf16.  ctx out: [b, s, 1024] bf16.
__global__ __launch_bounds__(256) void attn_mfma(
    const unsigned short* __restrict__ Qb, const unsigned short* __restrict__ Kb,
    const unsigned short* __restrict__ Vt, unsigned short* __restrict__ ctx) {
  __shared__ unsigned short P[4][16][40];  // per-wave P tile, padded stride 40
  const int wave = threadIdx.x >> 6;
  const int lane = threadIdx.x & 63;
  const int gw = (blockIdx.x << 2) + wave;
  const int bh = gw >> 7;           // 0..31
  const int i0 = (gw & 127) << 4;   // query tile start
  const int qr = lane & 15;
  const int kg = lane >> 4;         // 0..3
  const int kc = kg << 3;           // k-offset

  // Q A-fragments (row = query qr, k = dim)
  const size_t qbase = ((size_t)(bh * 2048 + i0 + qr)) * 64;
  const bf16x8 aq0 = ld16(Qb + qbase + kc);
  const bf16x8 aq1 = ld16(Qb + qbase + 32 + kc);

  // QK^T: 2 key-tiles x 2 k-steps. B-frag: row = key (lane&15), k = dim.
  f32x4 sc0 = {0.f, 0.f, 0.f, 0.f}, sc1 = {0.f, 0.f, 0.f, 0.f};
  {
    const int ka0 = i0 - 8 + qr;
    const int ka1 = ka0 + 16;
    const int kcl0 = min(max(ka0, 0), 2047);
    const int kcl1 = min(max(ka1, 0), 2047);
    const unsigned short* K0 = Kb + ((size_t)(bh * 2048 + kcl0)) * 64;
    const unsigned short* K1 = Kb + ((size_t)(bh * 2048 + kcl1)) * 64;
    sc0 = __builtin_amdgcn_mfma_f32_16x16x32_bf16(aq0, ld16(K0 + kc), sc0, 0, 0, 0);
    sc0 = __builtin_amdgcn_mfma_f32_16x16x32_bf16(aq1, ld16(K0 + 32 + kc), sc0, 0, 0, 0);
    sc1 = __builtin_amdgcn_mfma_f32_16x16x32_bf16(aq0, ld16(K1 + kc), sc1, 0, 0, 0);
    sc1 = __builtin_amdgcn_mfma_f32_16x16x32_bf16(aq1, ld16(K1 + 32 + kc), sc1, 0, 0, 0);
  }

  // mask + exp (no max-subtraction: |score| <= |q||k|/8, exp finite in fp32),
  // row-sum over 32 keys, stash P (bf16) in wave-private LDS.
  unsigned short* Pw = &P[wave][0][0];
  float lsum[4];
#pragma unroll
  for (int r = 0; r < 4; ++r) {
    const int q = (kg << 2) + r;   // score row = query
    const int key0 = qr, key1 = 16 + qr;
    const int ka0 = i0 - 8 + key0, ka1 = i0 - 8 + key1;
    const bool v0 = (q <= key0) && (key0 <= q + 16) && (ka0 >= 0) && (ka0 < 2048);
    const bool v1 = (q <= key1) && (key1 <= q + 16) && (ka1 >= 0) && (ka1 < 2048);
    const float e0 = v0 ? __expf(sc0[r] * 0.125f) : 0.f;
    const float e1 = v1 ? __expf(sc1[r] * 0.125f) : 0.f;
    Pw[q * 40 + key0] = f2bf(e0);
    Pw[q * 40 + key1] = f2bf(e1);
    float s = e0 + e1;
#pragma unroll
    for (int off = 1; off < 16; off <<= 1) s += __shfl_xor(s, off);
    lsum[r] = s;  // sum for query q, matches C-layout rows below
  }

  // P A-fragment: row = query qr, k = key
  const bf16x8 pa = ld16(&Pw[qr * 40 + kc]);

  // PV: 4 d-tiles, K=32 keys in one MFMA. B-frag from Vt: row = d, k = key.
  const int base_s = min(max(i0 - 8 + kc, 0), 2040);  // clamped chunks are fully masked
  f32x4 o[4];
  const f32x4 zero = {0.f, 0.f, 0.f, 0.f};
#pragma unroll
  for (int t2 = 0; t2 < 4; ++t2) {
    const unsigned short* Vr =
        Vt + ((size_t)(bh * 64 + t2 * 16 + qr)) * 2048 + base_s;
    o[t2] = __builtin_amdgcn_mfma_f32_16x16x32_bf16(pa, ld16(Vr), zero, 0, 0, 0);
  }

  // normalize + write ctx [b, s, 1024]
  const int b = bh >> 4, h = bh & 15;
  float rinv[4];
#pragma unroll
  for (int r = 0; r < 4; ++r) rinv[r] = 1.0f / lsum[r];
#pragma unroll
  for (int t2 = 0; t2 < 4; ++t2) {
#pragma unroll
    for (int r = 0; r < 4; ++r) {
      const int q = (kg << 2) + r;
      const int d = t2 * 16 + qr;
      ctx[((size_t)(b * 2048 + i0 + q)) * 1024 + (h << 6) + d] =
          f2bf(o[t2][r] * rinv[r]);
    }
  }
}

// ---------------------------------------------------------------------------
extern "C" void kernel_launch(void* const* d_in, const int* in_sizes, int n_in,
                              void* d_out, int out_size, void* d_ws,
                              size_t ws_size, hipStream_t stream) {
  const float* x = (const float*)d_in[0];      // [2,2048,1024]
  // d_in[1] token_ids: unused by reference
  const float* w_qkv = (const float*)d_in[2];  // [3072,1024]
  const float* b_qkv = (const float*)d_in[3];  // [3072]
  const float* w_out = (const float*)d_in[4];  // [1024,1024]
  const float* b_out = (const float*)d_in[5];  // [1024]
  float* out = (float*)d_out;                  // [2,2048,1024] fp32

  char* ws = (char*)d_ws;
  unsigned short* xb    = (unsigned short*)(ws + 0);         // 8 MB
  unsigned short* wqkvb = (unsigned short*)(ws + 8388608);   // 6 MB
  unsigned short* woutb = (unsigned short*)(ws + 14680064);  // 2 MB
  unsigned short* Qb    = (unsigned short*)(ws + 16777216);  // 8 MB [bh,s,64]
  unsigned short* Kb    = (unsigned short*)(ws + 25165824);  // 8 MB [bh,s,64]
  unsigned short* Vt    = (unsigned short*)(ws + 33554432);  // 8 MB [bh,d,2048]
  unsigned short* ctxb  = (unsigned short*)(ws + 41943040);  // 8 MB [b,s,1024]

  // fp32 -> bf16 conversions, one launch (grid-stride)
  cvt_all<<<2048, 256, 0, stream>>>(x, w_qkv, w_out, xb, wqkvb, woutb);

  // QKV projection: M=4096, N=3072, K=1024 -> bf16 Q/K/Vt scatter
  gemm_bt<1><<<dim3(32, 24), 256, 0, stream>>>(xb, wqkvb, b_qkv, Qb, Kb, Vt,
                                               nullptr, 4096, 3072, 1024);

  // sliding attention: 4096 waves (16 queries each), 4 waves/block
  attn_mfma<<<1024, 256, 0, stream>>>(Qb, Kb, Vt, ctxb);

  // out projection: M=4096, N=1024, K=1024 -> fp32 d_out
  gemm_bt<0><<<dim3(32, 8), 256, 0, stream>>>(ctxb, woutb, b_out, nullptr,
                                              nullptr, nullptr, out, 4096,
                                              1024, 1024);
}

// Round 5
// 79.734 us; speedup vs baseline: 1.4396x; 1.0083x over previous
//
#include <hip/hip_runtime.h>
#include <stdint.h>

// ---------------------------------------------------------------------------
// SlidingAttentionModule: B=2, S=2048, D=1024, H=16, hd=64, window +-8
//   qkv = x @ w_qkv^T + b_qkv     (bf16 MFMA GEMM -> Q,K [bh,s,d], V^T [bh,d,s])
//   attn: MFMA-tiled 16-query x 32-key sliding window, no max-subtraction
//   out = ctx @ w_out^T + b_out   (bf16 MFMA GEMM, fp32 out)
// GEMM: 128x128 tile, BK=64, 2-deep K-tile pipeline with COUNTED vmcnt(8)
//       (raw s_barrier; never drains to 0 in main loop — T3/T4), swizzled
//       conflict-free LDS layout from round 4 (slot^=(row&7), source
//       pre-permuted within 128B row segments; dest linear for gld_lds).
// ---------------------------------------------------------------------------

typedef __bf16 bf16_t;
typedef bf16_t bf16x8 __attribute__((ext_vector_type(8)));
typedef unsigned short u16x8 __attribute__((ext_vector_type(8)));
typedef float f32x4 __attribute__((ext_vector_type(4)));

#define GLD16(g, l)                                                        \
  __builtin_amdgcn_global_load_lds(                                        \
      (const __attribute__((address_space(1))) void*)(g),                  \
      (__attribute__((address_space(3))) void*)(l), 16, 0, 0)

__device__ __forceinline__ unsigned short f2bf(float f) {
  unsigned int u = __float_as_uint(f);
  u += 0x7FFFu + ((u >> 16) & 1u);  // round-to-nearest-even
  return (unsigned short)(u >> 16);
}

__device__ __forceinline__ bf16x8 ld16(const unsigned short* p) {
  return __builtin_bit_cast(bf16x8, *reinterpret_cast<const u16x8*>(p));
}

// --- fp32 -> bf16 conversion of all three tensors, one launch ---------------
__global__ void cvt_all(const float* __restrict__ x, const float* __restrict__ wq,
                        const float* __restrict__ wo, unsigned short* __restrict__ xb,
                        unsigned short* __restrict__ wqb,
                        unsigned short* __restrict__ wob) {
  const int N0 = 1048576, N1 = 786432, N2 = 262144;  // float4 counts
  for (int i = blockIdx.x * blockDim.x + threadIdx.x; i < N0 + N1 + N2;
       i += gridDim.x * blockDim.x) {
    const float4* src;
    unsigned short* dst;
    int j;
    if (i < N0) { src = (const float4*)x; dst = xb; j = i; }
    else if (i < N0 + N1) { src = (const float4*)wq; dst = wqb; j = i - N0; }
    else { src = (const float4*)wo; dst = wob; j = i - N0 - N1; }
    const float4 f = src[j];
    ushort4 o;
    o.x = f2bf(f.x); o.y = f2bf(f.y); o.z = f2bf(f.z); o.w = f2bf(f.w);
    reinterpret_cast<ushort4*>(dst)[j] = o;
  }
}

// --- bf16 GEMM: C[m,n] = sum_k A[m,k]*Bt[n,k] + bias[n] ---------------------
// LDS per buffer: row-major [128][64] ushort; 16B slot s of row r holds global
//   k-slot s ^ (r&7). Stage: lane u -> row wave*8+(u>>3) (+r*32), global slot
//   ((u&7)^(u>>3)); dest linear (wave base + lane*16B). 8 lanes span one 128B
//   row segment (permuted within) -> coalescing preserved.
// Pipeline: 2 buffers, stage 2 K-tiles ahead, counted s_waitcnt vmcnt(8),
//   raw s_barrier pair per K-tile (see header comment for safety argument).
// EPI=0: plain fp32 write to Cp[m*N+n].
// EPI=1: scatter bf16 q/k into [bh,s,64], v into [bh,d,2048] (transposed).
template <int EPI>
__global__ __launch_bounds__(256, 2) void gemm_bt(
    const unsigned short* __restrict__ A,   // [M,K] bf16 bits
    const unsigned short* __restrict__ Bt,  // [N,K] bf16 bits
    const float* __restrict__ bias,         // [N]
    unsigned short* __restrict__ Cq, unsigned short* __restrict__ Ck,
    unsigned short* __restrict__ Cv, float* __restrict__ Cp, int M, int N,
    int K) {
  __shared__ unsigned short sA[2][8192];
  __shared__ unsigned short sB[2][8192];

  const int tid = threadIdx.x;
  const int wave = tid >> 6;
  const int lane = tid & 63;
  const int m0 = blockIdx.x * 128;
  const int n0 = blockIdx.y * 128;
  const int wr = wave >> 1;
  const int wc = wave & 1;

  f32x4 acc[4][4] = {};

  // staging source (round-4 proven mapping)
  const int srow = (wave << 3) + (lane >> 3);
  const int sslot = ((lane & 7) ^ (lane >> 3)) << 3;  // elem offset in row
  const unsigned short* Ag = A + (size_t)(m0 + srow) * K + sslot;
  const unsigned short* Bg = Bt + (size_t)(n0 + srow) * K + sslot;
  const int wdst = wave * 512;  // ushort offset; +r*2048; +lane*8 implicit

  const int T = K >> 6;  // K-tiles of 64

  auto stage = [&](int t, int b) {
#pragma unroll
    for (int r = 0; r < 4; ++r) {
      GLD16(Ag + (size_t)(r * 32) * K + t * 64, &sA[b][r * 2048 + wdst]);
      GLD16(Bg + (size_t)(r * 32) * K + t * 64, &sB[b][r * 2048 + wdst]);
    }
  };

  // prologue: 2 K-tiles in flight (16 loads/thread)
  stage(0, 0);
  stage(1, 1);

  const int kg = lane >> 4;
  const int l7 = lane & 7;
  const int arr = wr * 64 + (lane & 15);
  const int brr = wc * 64 + (lane & 15);

  for (int t = 0; t < T; ++t) {
    // wait for tile t's DMA (8 loads of tile t+1 may stay in flight)
    if (t < T - 1)
      asm volatile("s_waitcnt vmcnt(8)" ::: "memory");
    else
      asm volatile("s_waitcnt vmcnt(0)" ::: "memory");
    __builtin_amdgcn_s_barrier();  // all waves' tile-t loads landed

    const int b = t & 1;
    const unsigned short* sAb = sA[b];
    const unsigned short* sBb = sB[b];
    bf16x8 af[2][4], bfr[2][4];
#pragma unroll
    for (int st = 0; st < 2; ++st) {
#pragma unroll
      for (int f = 0; f < 4; ++f) {
        const int se = ((st << 2) | kg) ^ l7;
        af[st][f] = ld16(&sAb[(arr + f * 16) * 64 + (se << 3)]);
        bfr[st][f] = ld16(&sBb[(brr + f * 16) * 64 + (se << 3)]);
      }
    }
    asm volatile("s_waitcnt lgkmcnt(0)" ::: "memory");  // frags in regs
    __builtin_amdgcn_sched_barrier(0);                  // rule #18
    __builtin_amdgcn_s_barrier();  // all waves done reading buf b

    if (t + 2 < T) stage(t + 2, b);  // overwrite now safe; hidden by MFMAs

#pragma unroll
    for (int st = 0; st < 2; ++st)
#pragma unroll
      for (int i = 0; i < 4; ++i)
#pragma unroll
        for (int j = 0; j < 4; ++j)
          acc[i][j] = __builtin_amdgcn_mfma_f32_16x16x32_bf16(
              af[st][i], bfr[st][j], acc[i][j], 0, 0, 0);
  }

  // epilogue: C/D layout col = lane&15, row = (lane>>4)*4 + reg  [m89]
#pragma unroll
  for (int i = 0; i < 4; ++i) {
    const int row0 = m0 + wr * 64 + i * 16 + ((lane >> 4) << 2);
#pragma unroll
    for (int j = 0; j < 4; ++j) {
      const int col = n0 + wc * 64 + j * 16 + (lane & 15);
      const float bb = bias[col];
#pragma unroll
      for (int r = 0; r < 4; ++r) {
        const int m = row0 + r;
        const float val = acc[i][j][r] + bb;
        if (EPI == 0) {
          Cp[(size_t)m * N + col] = val;
        } else {
          const int b2 = m >> 11, s = m & 2047;
          const int which = col >> 10, nn = col & 1023;
          const int h = nn >> 6, d = nn & 63;
          const int bh = (b2 << 4) + h;
          const unsigned short vb = f2bf(val);
          if (which == 0)
            Cq[((size_t)(bh * 2048 + s)) * 64 + d] = vb;
          else if (which == 1)
            Ck[((size_t)(bh * 2048 + s)) * 64 + d] = vb;
          else
            Cv[((size_t)(bh * 64 + d)) * 2048 + s] = vb;
        }
      }
    }
  }
}

// --- MFMA sliding attention: 1 wave = 16 queries x 32-key window ------------
// Q,K: [bh, s, 64] bf16.  Vt: [bh, d, 2048] bf16.  ctx out: [b, s, 1024] bf16.
__global__ __launch_bounds__(256) void attn_mfma(
    const unsigned short* __restrict__ Qb, const unsigned short* __restrict__ Kb,
    const unsigned short* __restrict__ Vt, unsigned short* __restrict__ ctx) {
  __shared__ unsigned short P[4][16][40];  // per-wave P tile, padded stride 40
  const int wave = threadIdx.x >> 6;
  const int lane = threadIdx.x & 63;
  const int gw = (blockIdx.x << 2) + wave;
  const int bh = gw >> 7;           // 0..31
  const int i0 = (gw & 127) << 4;   // query tile start
  const int qr = lane & 15;
  const int kg = lane >> 4;         // 0..3
  const int kc = kg << 3;           // k-offset

  // Q A-fragments (row = query qr, k = dim)
  const size_t qbase = ((size_t)(bh * 2048 + i0 + qr)) * 64;
  const bf16x8 aq0 = ld16(Qb + qbase + kc);
  const bf16x8 aq1 = ld16(Qb + qbase + 32 + kc);

  // QK^T: 2 key-tiles x 2 k-steps. B-frag: row = key (lane&15), k = dim.
  f32x4 sc0 = {0.f, 0.f, 0.f, 0.f}, sc1 = {0.f, 0.f, 0.f, 0.f};
  {
    const int ka0 = i0 - 8 + qr;
    const int ka1 = ka0 + 16;
    const int kcl0 = min(max(ka0, 0), 2047);
    const int kcl1 = min(max(ka1, 0), 2047);
    const unsigned short* K0 = Kb + ((size_t)(bh * 2048 + kcl0)) * 64;
    const unsigned short* K1 = Kb + ((size_t)(bh * 2048 + kcl1)) * 64;
    sc0 = __builtin_amdgcn_mfma_f32_16x16x32_bf16(aq0, ld16(K0 + kc), sc0, 0, 0, 0);
    sc0 = __builtin_amdgcn_mfma_f32_16x16x32_bf16(aq1, ld16(K0 + 32 + kc), sc0, 0, 0, 0);
    sc1 = __builtin_amdgcn_mfma_f32_16x16x32_bf16(aq0, ld16(K1 + kc), sc1, 0, 0, 0);
    sc1 = __builtin_amdgcn_mfma_f32_16x16x32_bf16(aq1, ld16(K1 + 32 + kc), sc1, 0, 0, 0);
  }

  // mask + exp (no max-subtraction: |score| <= |q||k|/8, exp finite in fp32),
  // row-sum over 32 keys, stash P (bf16) in wave-private LDS.
  unsigned short* Pw = &P[wave][0][0];
  float lsum[4];
#pragma unroll
  for (int r = 0; r < 4; ++r) {
    const int q = (kg << 2) + r;   // score row = query
    const int key0 = qr, key1 = 16 + qr;
    const int ka0 = i0 - 8 + key0, ka1 = i0 - 8 + key1;
    const bool v0 = (q <= key0) && (key0 <= q + 16) && (ka0 >= 0) && (ka0 < 2048);
    const bool v1 = (q <= key1) && (key1 <= q + 16) && (ka1 >= 0) && (ka1 < 2048);
    const float e0 = v0 ? __expf(sc0[r] * 0.125f) : 0.f;
    const float e1 = v1 ? __expf(sc1[r] * 0.125f) : 0.f;
    Pw[q * 40 + key0] = f2bf(e0);
    Pw[q * 40 + key1] = f2bf(e1);
    float s = e0 + e1;
#pragma unroll
    for (int off = 1; off < 16; off <<= 1) s += __shfl_xor(s, off);
    lsum[r] = s;  // sum for query q, matches C-layout rows below
  }

  // P A-fragment: row = query qr, k = key
  const bf16x8 pa = ld16(&Pw[qr * 40 + kc]);

  // PV: 4 d-tiles, K=32 keys in one MFMA. B-frag from Vt: row = d, k = key.
  const int base_s = min(max(i0 - 8 + kc, 0), 2040);  // clamped chunks are fully masked
  f32x4 o[4];
  const f32x4 zero = {0.f, 0.f, 0.f, 0.f};
#pragma unroll
  for (int t2 = 0; t2 < 4; ++t2) {
    const unsigned short* Vr =
        Vt + ((size_t)(bh * 64 + t2 * 16 + qr)) * 2048 + base_s;
    o[t2] = __builtin_amdgcn_mfma_f32_16x16x32_bf16(pa, ld16(Vr), zero, 0, 0, 0);
  }

  // normalize + write ctx [b, s, 1024]
  const int b = bh >> 4, h = bh & 15;
  float rinv[4];
#pragma unroll
  for (int r = 0; r < 4; ++r) rinv[r] = 1.0f / lsum[r];
#pragma unroll
  for (int t2 = 0; t2 < 4; ++t2) {
#pragma unroll
    for (int r = 0; r < 4; ++r) {
      const int q = (kg << 2) + r;
      const int d = t2 * 16 + qr;
      ctx[((size_t)(b * 2048 + i0 + q)) * 1024 + (h << 6) + d] =
          f2bf(o[t2][r] * rinv[r]);
    }
  }
}

// ---------------------------------------------------------------------------
extern "C" void kernel_launch(void* const* d_in, const int* in_sizes, int n_in,
                              void* d_out, int out_size, void* d_ws,
                              size_t ws_size, hipStream_t stream) {
  const float* x = (const float*)d_in[0];      // [2,2048,1024]
  // d_in[1] token_ids: unused by reference
  const float* w_qkv = (const float*)d_in[2];  // [3072,1024]
  const float* b_qkv = (const float*)d_in[3];  // [3072]
  const float* w_out = (const float*)d_in[4];  // [1024,1024]
  const float* b_out = (const float*)d_in[5];  // [1024]
  float* out = (float*)d_out;                  // [2,2048,1024] fp32

  char* ws = (char*)d_ws;
  unsigned short* xb    = (unsigned short*)(ws + 0);         // 8 MB
  unsigned short* wqkvb = (unsigned short*)(ws + 8388608);   // 6 MB
  unsigned short* woutb = (unsigned short*)(ws + 14680064);  // 2 MB
  unsigned short* Qb    = (unsigned short*)(ws + 16777216);  // 8 MB [bh,s,64]
  unsigned short* Kb    = (unsigned short*)(ws + 25165824);  // 8 MB [bh,s,64]
  unsigned short* Vt    = (unsigned short*)(ws + 33554432);  // 8 MB [bh,d,2048]
  unsigned short* ctxb  = (unsigned short*)(ws + 41943040);  // 8 MB [b,s,1024]

  // fp32 -> bf16 conversions, one launch (grid-stride)
  cvt_all<<<2048, 256, 0, stream>>>(x, w_qkv, w_out, xb, wqkvb, woutb);

  // QKV projection: M=4096, N=3072, K=1024 -> bf16 Q/K/Vt scatter
  gemm_bt<1><<<dim3(32, 24), 256, 0, stream>>>(xb, wqkvb, b_qkv, Qb, Kb, Vt,
                                               nullptr, 4096, 3072, 1024);

  // sliding attention: 4096 waves (16 queries each), 4 waves/block
  attn_mfma<<<1024, 256, 0, stream>>>(Qb, Kb, Vt, ctxb);

  // out projection: M=4096, N=1024, K=1024 -> fp32 d_out
  gemm_bt<0><<<dim3(32, 8), 256, 0, stream>>>(ctxb, woutb, b_out, nullptr,
                                              nullptr, nullptr, out, 4096,
                                              1024, 1024);
}